// Round 1
// baseline (635.874 us; speedup 1.0000x reference)
//
#include <hip/hip_runtime.h>
#include <hip/hip_fp16.h>

// Stacked GRU (T=50, B=1, H=256) on MI355X.
// Design: parallel pre/post GEMM kernels + one persistent 32-block scan kernel.
// Scan partitions H=256 into 32 slices of 8; each block holds its 4x24x256 f16
// weight slice in LDS and the blocks synchronize 2x/step via a device-scope
// monotonic-counter barrier. All cross-block data uses agent-scope atomics
// (cross-XCD L2s are not coherent for plain cached accesses).

#define T_STEPS 50
#define VIN 768
#define VF 128
#define MIN_ 2
#define MF 128
#define H 256
#define G3 768

#define NB 32            // blocks in scan kernel
#define BT 256           // threads per scan block (4 waves)
#define HJ 8             // H / NB: h-elements owned per block
#define ROWS 24          // 3 gates * HJ rows per weight matrix slice
#define BAIL 10000000    // spin bailout (anti-wedge; never triggers when co-resident)

__device__ __forceinline__ float sigm(float x){ return 1.0f/(1.0f+expf(-x)); }
__device__ __forceinline__ float eluf(float x){ return x > 0.0f ? x : expm1f(x); }

// agent-scope (device-coherent) data access for cross-block shared state
__device__ __forceinline__ float gld(const float* p){
  return __hip_atomic_load(const_cast<float*>(p), __ATOMIC_RELAXED, __HIP_MEMORY_SCOPE_AGENT);
}
__device__ __forceinline__ void gst(float* p, float v){
  __hip_atomic_store(p, v, __ATOMIC_RELAXED, __HIP_MEMORY_SCOPE_AGENT);
}

// ---------------------------------------------------------------- pack weights
// Wpack layout: [b][m][lr][c_sw] f16, m: 0=Wih_low[:,256:512], 1=Whh_low,
// 2=Wih_high, 3=Whh_high. lr = g*8+j -> global row g*256 + b*8 + j.
// c_sw swizzle: element c=k*64+l stored at l*4+k so lane l reads 4 contiguous halfs.
__global__ __launch_bounds__(256) void pack_kernel(
    const float* __restrict__ Wih_low, const float* __restrict__ Whh_low,
    const float* __restrict__ Wih_high, const float* __restrict__ Whh_high,
    __half* __restrict__ Wpack)
{
  int d = blockIdx.x * 256 + threadIdx.x;     // 0 .. NB*4*ROWS*256-1
  int c_sw = d & 255;
  int rest = d >> 8;            // (b*4+m)*ROWS + lr
  int lr = rest % ROWS; rest /= ROWS;
  int m = rest & 3;
  int b = rest >> 2;
  int l = c_sw >> 2, k = c_sw & 3;
  int c = k * 64 + l;
  int g = lr / HJ, j = lr % HJ;
  int row = g * H + b * HJ + j;
  float v;
  if      (m == 0) v = Wih_low[row * (2*H) + H + c];   // h2-part columns [256,512)
  else if (m == 1) v = Whh_low[row * H + c];
  else if (m == 2) v = Wih_high[row * H + c];
  else             v = Whh_high[row * H + c];
  Wpack[d] = __float2half(v);
}

// ---------------------------------------------------------------- features X
// X[t] = [elu(W1v v0_t + b1v) | elu(W1m m0_t + b1m)]  (50 x 256)
__global__ __launch_bounds__(128) void feat_kernel(
    const float* __restrict__ v0, const float* __restrict__ m0,
    const float* __restrict__ W1v, const float* __restrict__ b1v,
    const float* __restrict__ W1m, const float* __restrict__ b1m,
    float* __restrict__ X)
{
  const int t = blockIdx.x, j = threadIdx.x;
  const float4* v4 = reinterpret_cast<const float4*>(v0 + t * VIN);
  const float4* w4 = reinterpret_cast<const float4*>(W1v + j * VIN);
  float acc = b1v[j];
  #pragma unroll 4
  for (int c = 0; c < VIN/4; ++c){
    float4 a = v4[c], w = w4[c];
    acc += a.x*w.x + a.y*w.y + a.z*w.z + a.w*w.w;
  }
  X[t*H + j] = eluf(acc);
  float am = b1m[j] + W1m[j*2]*m0[t*2] + W1m[j*2+1]*m0[t*2+1];
  X[t*H + VF + j] = eluf(am);
}

// ---------------------------------------------------------------- Gx precompute
// Gx[t][r] = bih_low[r] + sum_c Wih_low[r][c] * X[t][c]   (x-part, cols 0..255)
__global__ __launch_bounds__(G3) void gx_kernel(
    const float* __restrict__ Wih_low, const float* __restrict__ bih_low,
    const float* __restrict__ X, float* __restrict__ Gx)
{
  const int t = blockIdx.x, r = threadIdx.x;
  __shared__ float xs[H];
  if (r < H) xs[r] = X[t*H + r];
  __syncthreads();
  const float* w = Wih_low + r * (2*H);
  float acc = bih_low[r];
  #pragma unroll 8
  for (int c = 0; c < H; ++c) acc += w[c] * xs[c];
  Gx[t*G3 + r] = acc;
}

// ---------------------------------------------------------------- scan
__device__ __forceinline__ void gbar(unsigned* cnt, unsigned target){
  __syncthreads();
  if (threadIdx.x == 0){
    __threadfence();
    __hip_atomic_fetch_add(cnt, 1u, __ATOMIC_RELEASE, __HIP_MEMORY_SCOPE_AGENT);
    int guard = 0;
    while (__hip_atomic_load(cnt, __ATOMIC_ACQUIRE, __HIP_MEMORY_SCOPE_AGENT) < target){
      __builtin_amdgcn_s_sleep(2);
      if (++guard > BAIL) break;   // anti-wedge bailout
    }
    __threadfence();
  }
  __syncthreads();
}

// compute the 24 (gi,gh) dot pairs for one phase; wbase points at the gi matrix
// slice, gh matrix slice is at wbase + ROWS*256.
__device__ __forceinline__ void dot_phase(const __half* wbase, float g_lds[2][ROWS],
                                          const float* hA, const float* hB,
                                          int wv, int lane)
{
  float a0=gld(hA+lane), a1=gld(hA+64+lane), a2=gld(hA+128+lane), a3=gld(hA+192+lane);
  float b0=gld(hB+lane), b1=gld(hB+64+lane), b2=gld(hB+128+lane), b3=gld(hB+192+lane);
  #pragma unroll
  for (int rr = 0; rr < 6; ++rr){
    const int lr = wv*6 + rr;
    const __half2* w0 = reinterpret_cast<const __half2*>(wbase + (lr << 8));
    const __half2* w1 = reinterpret_cast<const __half2*>(wbase + ((ROWS + lr) << 8));
    float2 f00 = __half22float2(w0[2*lane]);
    float2 f01 = __half22float2(w0[2*lane+1]);
    float2 f10 = __half22float2(w1[2*lane]);
    float2 f11 = __half22float2(w1[2*lane+1]);
    float gi = f00.x*a0 + f00.y*a1 + f01.x*a2 + f01.y*a3;
    float gh = f10.x*b0 + f10.y*b1 + f11.x*b2 + f11.y*b3;
    #pragma unroll
    for (int off = 32; off; off >>= 1){
      gi += __shfl_xor(gi, off);
      gh += __shfl_xor(gh, off);
    }
    if (lane == 0){ g_lds[0][lr] = gi; g_lds[1][lr] = gh; }
  }
}

__global__ __launch_bounds__(BT) void scan_kernel(
    const __half* __restrict__ Wpack,
    const float* __restrict__ Gx,
    const float* __restrict__ bhh_low,
    const float* __restrict__ bih_high,
    const float* __restrict__ bhh_high,
    float* h1buf, float* h2buf,            // [2][H] each, zeroed by memset
    float* __restrict__ h1out,             // [T][H]
    unsigned* cnt)                         // zeroed by memset
{
  __shared__ __half w_lds[4*ROWS*256];
  __shared__ float g_lds[2][ROWS];
  const int tid = threadIdx.x;
  const int b = blockIdx.x;
  const int wv = tid >> 6, lane = tid & 63;

  { // stage this block's weight slice into LDS (48 KB)
    const uint2* src = reinterpret_cast<const uint2*>(Wpack + (size_t)b * 4*ROWS*256);
    uint2* dst = reinterpret_cast<uint2*>(w_lds);
    for (int i = tid; i < 4*ROWS*256/4; i += BT) dst[i] = src[i];
  }
  __syncthreads();

  unsigned bar = 0;
  for (int t = 0; t < T_STEPS; ++t){
    const int p = t & 1;
    float* h1o = h1buf + p*H;       float* h1n = h1buf + (1-p)*H;
    float* h2o = h2buf + p*H;       float* h2n = h2buf + (1-p)*H;

    // ---- phase A: low cell. gi += Wl2*h2_old ; gh = Whh_low*h1_old ----
    dot_phase(w_lds, g_lds, h2o, h1o, wv, lane);
    __syncthreads();
    if (tid < HJ){
      const int jg = b*HJ + tid;
      const float* gx = Gx + t*G3;
      float giR = g_lds[0][tid]        + gx[jg];
      float ghR = g_lds[1][tid]        + bhh_low[jg];
      float giZ = g_lds[0][HJ+tid]     + gx[H + jg];
      float ghZ = g_lds[1][HJ+tid]     + bhh_low[H + jg];
      float giN = g_lds[0][2*HJ+tid]   + gx[2*H + jg];
      float ghN = g_lds[1][2*HJ+tid]   + bhh_low[2*H + jg];
      float r = sigm(giR + ghR), z = sigm(giZ + ghZ);
      float n = tanhf(giN + r * ghN);
      float hv = (1.0f - z) * n + z * gld(h1o + jg);
      gst(h1n + jg, hv);
      h1out[t*H + jg] = hv;          // kernel-boundary visibility is enough
    }
    if (t == T_STEPS - 1) break;     // uniform across all blocks
    gbar(cnt, (++bar) * NB);

    // ---- phase B: high cell. gi = Wih_high*h1_new ; gh = Whh_high*h2_old ----
    dot_phase(w_lds + 2*ROWS*256, g_lds, h1n, h2o, wv, lane);
    __syncthreads();
    if (tid < HJ){
      const int jg = b*HJ + tid;
      float giR = g_lds[0][tid]        + bih_high[jg];
      float ghR = g_lds[1][tid]        + bhh_high[jg];
      float giZ = g_lds[0][HJ+tid]     + bih_high[H + jg];
      float ghZ = g_lds[1][HJ+tid]     + bhh_high[H + jg];
      float giN = g_lds[0][2*HJ+tid]   + bih_high[2*H + jg];
      float ghN = g_lds[1][2*HJ+tid]   + bhh_high[2*H + jg];
      float r = sigm(giR + ghR), z = sigm(giZ + ghZ);
      float n = tanhf(giN + r * ghN);
      float hv = (1.0f - z) * n + z * gld(h2o + jg);
      gst(h2n + jg, hv);
    }
    gbar(cnt, (++bar) * NB);
  }
}

// ---------------------------------------------------------------- post
// v_n[t] = sigmoid(W2v elu(h1[:128]) + b2v);  m_n[t] = tanh(W2m elu(h1[128:256]) + b2m)
__global__ __launch_bounds__(G3) void post_kernel(
    const float* __restrict__ h1out,
    const float* __restrict__ W2v, const float* __restrict__ b2v,
    const float* __restrict__ W2m, const float* __restrict__ b2m,
    float* __restrict__ out)
{
  const int t = blockIdx.x, r = threadIdx.x;
  __shared__ float fs[H];
  if (r < H) fs[r] = eluf(h1out[t*H + r]);
  __syncthreads();
  const float* w = W2v + r * VF;
  float acc = b2v[r];
  #pragma unroll 8
  for (int c = 0; c < VF; ++c) acc += w[c] * fs[c];
  out[t*VIN + r] = sigm(acc);
  if (r < MIN_){
    const float* wm = W2m + r * VF;
    float am = b2m[r];
    #pragma unroll 8
    for (int c = 0; c < VF; ++c) am += wm[c] * fs[VF + c];
    out[T_STEPS*VIN + t*MIN_ + r] = tanhf(am);
  }
}

extern "C" void kernel_launch(void* const* d_in, const int* in_sizes, int n_in,
                              void* d_out, int out_size, void* d_ws, size_t ws_size,
                              hipStream_t stream)
{
  const float* v0       = (const float*)d_in[0];
  const float* m0       = (const float*)d_in[1];
  const float* W1v      = (const float*)d_in[2];
  const float* b1v      = (const float*)d_in[3];
  const float* W1m      = (const float*)d_in[4];
  const float* b1m      = (const float*)d_in[5];
  const float* Wih_low  = (const float*)d_in[6];
  const float* Whh_low  = (const float*)d_in[7];
  const float* bih_low  = (const float*)d_in[8];
  const float* bhh_low  = (const float*)d_in[9];
  const float* Wih_high = (const float*)d_in[10];
  const float* Whh_high = (const float*)d_in[11];
  const float* bih_high = (const float*)d_in[12];
  const float* bhh_high = (const float*)d_in[13];
  const float* W2v      = (const float*)d_in[14];
  const float* b2v      = (const float*)d_in[15];
  const float* W2m      = (const float*)d_in[16];
  const float* b2m      = (const float*)d_in[17];
  float* out = (float*)d_out;

  // ws layout (256-aligned):
  char* ws = (char*)d_ws;
  unsigned* cnt  = (unsigned*)(ws + 0);                  // 4 B (reserve 256)
  float* h1buf   = (float*)(ws + 256);                   // 2*256 f32 = 2048 B
  float* h2buf   = (float*)(ws + 2560);                  // 2048 B
  float* X       = (float*)(ws + 4864);                  // 50*256 f32 = 51200 B
  float* Gx      = (float*)(ws + 4864 + 51200);          // 50*768 f32 = 153600 B
  float* h1out   = (float*)(ws + 4864 + 51200 + 153600); // 51200 B
  __half* Wpack  = (__half*)(ws + 4864 + 51200 + 153600 + 51200); // 1.5 MB

  // zero barrier counter + h state (ws is poisoned 0xAA before every launch)
  hipMemsetAsync(ws, 0, 4864, stream);

  pack_kernel<<<(NB*4*ROWS*256)/256, 256, 0, stream>>>(Wih_low, Whh_low, Wih_high, Whh_high, Wpack);
  feat_kernel<<<T_STEPS, 128, 0, stream>>>(v0, m0, W1v, b1v, W1m, b1m, X);
  gx_kernel<<<T_STEPS, G3, 0, stream>>>(Wih_low, bih_low, X, Gx);
  scan_kernel<<<NB, BT, 0, stream>>>(Wpack, Gx, bhh_low, bih_high, bhh_high,
                                     h1buf, h2buf, h1out, cnt);
  post_kernel<<<T_STEPS, G3, 0, stream>>>(h1out, W2v, b2v, W2m, b2m, out);
}

// Round 2
// 563.800 us; speedup vs baseline: 1.1278x; 1.1278x over previous
//
#include <hip/hip_runtime.h>
#include <hip/hip_fp16.h>

// Stacked GRU (T=50, B=1, H=256) on MI355X — round 2.
// Barrier-free scan: cross-block h exchange via 64-bit tagged atomics
// (tag = step+1, value = f32 bits) with relaxed agent-scope load/store.
// No fences, no central counter. Software-pipelined so the independent
// matrix of each phase hides the store->load propagation latency.

#define T_STEPS 50
#define VIN 768
#define VF 128
#define MIN_ 2
#define H 256
#define G3 768

#define NB 32            // blocks in scan kernel
#define BT 256           // threads per scan block (4 waves)
#define HJ 8             // H / NB
#define ROWS 24          // 3*HJ rows per matrix slice
#define WSLICE (4*ROWS*256)
#define BAIL 2000000     // poll bailout (anti-wedge)

typedef unsigned long long u64;

__device__ __forceinline__ float sigm(float x){ return 1.0f/(1.0f+expf(-x)); }
__device__ __forceinline__ float eluf(float x){ return x > 0.0f ? x : expm1f(x); }

__device__ __forceinline__ u64 ald(const u64* p){
  return __hip_atomic_load(const_cast<u64*>(p), __ATOMIC_RELAXED, __HIP_MEMORY_SCOPE_AGENT);
}
__device__ __forceinline__ void ast(u64* p, u64 v){
  __hip_atomic_store(p, v, __ATOMIC_RELAXED, __HIP_MEMORY_SCOPE_AGENT);
}
__device__ __forceinline__ u64 packtv(unsigned tag, float v){
  union{ float f; unsigned u; } c; c.f = v;
  return ((u64)tag << 32) | (u64)c.u;
}
__device__ __forceinline__ float unpackv(u64 x){
  union{ unsigned u; float f; } c; c.u = (unsigned)x; return c.f;
}

// poll 4 tagged elements (lane, 64+lane, 128+lane, 192+lane) until tag matches
__device__ __forceinline__ void poll4(const u64* base, int lane, unsigned tag, float v[4]){
  u64 x0=0,x1=0,x2=0,x3=0;
  bool o0=false,o1=false,o2=false,o3=false;
  int guard = 0;
  while (true){
    if(!o0){ x0 = ald(base +       lane); o0 = ((unsigned)(x0>>32) == tag); }
    if(!o1){ x1 = ald(base +  64 + lane); o1 = ((unsigned)(x1>>32) == tag); }
    if(!o2){ x2 = ald(base + 128 + lane); o2 = ((unsigned)(x2>>32) == tag); }
    if(!o3){ x3 = ald(base + 192 + lane); o3 = ((unsigned)(x3>>32) == tag); }
    if (o0 & o1 & o2 & o3) break;
    if (++guard > BAIL) break;       // anti-wedge
    __builtin_amdgcn_s_sleep(1);
  }
  v[0]=unpackv(x0); v[1]=unpackv(x1); v[2]=unpackv(x2); v[3]=unpackv(x3);
}

// one 24x256 matrix-slice matvec: lane holds v[k]=h[k*64+lane]; weights swizzled
// so lane's 4 cols are contiguous halfs. lane0 writes out[lr].
__device__ __forceinline__ void dot_one(const __half* wm, const float v[4],
                                        float* out, int wv, int lane){
  #pragma unroll
  for (int rr = 0; rr < 6; ++rr){
    const int lr = wv*6 + rr;
    const __half2* w = reinterpret_cast<const __half2*>(wm + (lr << 8));
    float2 f0 = __half22float2(w[2*lane]);
    float2 f1 = __half22float2(w[2*lane+1]);
    float s = f0.x*v[0] + f0.y*v[1] + f1.x*v[2] + f1.y*v[3];
    #pragma unroll
    for (int off = 32; off; off >>= 1) s += __shfl_xor(s, off);
    if (lane == 0) out[lr] = s;
  }
}

// ---------------------------------------------------------------- feat + Gx
// block t: xs = [elu(W1v v0_t + b1v) | elu(W1m m0_t + b1m)] then
// Gx[t][r] = bih_low[r] + Wih_low[r][0:256] . xs
__global__ __launch_bounds__(G3) void featgx_kernel(
    const float* __restrict__ v0, const float* __restrict__ m0,
    const float* __restrict__ W1v, const float* __restrict__ b1v,
    const float* __restrict__ W1m, const float* __restrict__ b1m,
    const float* __restrict__ Wih_low, const float* __restrict__ bih_low,
    float* __restrict__ Gx)
{
  const int t = blockIdx.x, tid = threadIdx.x;
  __shared__ float xs[H];
  if (tid < 512){
    const int j = tid >> 2, s = tid & 3;                 // 4 threads per output j
    const float4* a4 = reinterpret_cast<const float4*>(v0 + t*VIN + s*192);
    const float4* w4 = reinterpret_cast<const float4*>(W1v + j*VIN + s*192);
    float p = 0.f;
    #pragma unroll 4
    for (int c = 0; c < 48; ++c){
      float4 a = a4[c], w = w4[c];
      p += a.x*w.x + a.y*w.y + a.z*w.z + a.w*w.w;
    }
    p += __shfl_xor(p, 1);
    p += __shfl_xor(p, 2);
    if (s == 0) xs[j] = eluf(p + b1v[j]);
  } else if (tid < 640){
    const int j = tid - 512;
    float am = b1m[j] + W1m[j*2]*m0[t*2] + W1m[j*2+1]*m0[t*2+1];
    xs[VF + j] = eluf(am);
  }
  __syncthreads();
  const int r = tid;
  const float* w = Wih_low + r * (2*H);
  float acc = bih_low[r];
  #pragma unroll 8
  for (int c = 0; c < H; ++c) acc += w[c] * xs[c];
  Gx[t*G3 + r] = acc;
}

// ---------------------------------------------------------------- scan
__global__ __launch_bounds__(BT) void scan_kernel(
    const float* __restrict__ Wih_low, const float* __restrict__ Whh_low,
    const float* __restrict__ Wih_high, const float* __restrict__ Whh_high,
    const float* __restrict__ Gx,
    const float* __restrict__ bhh_low,
    const float* __restrict__ bih_high,
    const float* __restrict__ bhh_high,
    u64* h1s, u64* h2s,                    // [2][256] tagged, memset 0
    float* __restrict__ h1out)             // [T][256]
{
  __shared__ __half w_lds[WSLICE];         // [m][lr][c_sw]; m: 0=Wl2 1=Whh_low 2=Wih_high 3=Whh_high
  __shared__ float gA[2*ROWS];             // [0..23]=gi_A, [24..47]=gh_A
  __shared__ float gB[2*ROWS];
  const int tid = threadIdx.x;
  const int b = blockIdx.x;
  const int wv = tid >> 6, lane = tid & 63;

  // ---- gather+pack this block's weight slice into LDS (f32 -> f16, swizzled)
  #pragma unroll 4
  for (int i = tid; i < WSLICE; i += BT){
    int c_sw = i & 255;
    int r2 = i >> 8;                       // m*ROWS + lr
    int lr = r2 % ROWS, m = r2 / ROWS;
    int c = (c_sw & 3)*64 + (c_sw >> 2);
    int g = lr / HJ, j = lr % HJ;
    int row = g*H + b*HJ + j;
    float v;
    if      (m == 0) v = Wih_low [row*(2*H) + H + c];   // h2-columns of Wih_low
    else if (m == 1) v = Whh_low [row*H + c];
    else if (m == 2) v = Wih_high[row*H + c];
    else             v = Whh_high[row*H + c];
    w_lds[i] = __float2half(v);
  }
  if (tid < 2*ROWS) gA[tid] = 0.f;         // h1[-1]=h2[-1]=0 -> phase-A dots are 0
  __syncthreads();

  const __half* w_m0 = w_lds;              // Wl2       (gi_A part)
  const __half* w_m1 = w_lds + 1*ROWS*256; // Whh_low   (gh_A)
  const __half* w_m2 = w_lds + 2*ROWS*256; // Wih_high  (gi_B)
  const __half* w_m3 = w_lds + 3*ROWS*256; // Whh_high  (gh_B)

  // per-thread state
  float az[4] = {0.f,0.f,0.f,0.f};         // lane's 4 elems of h2[t-1]
  float nh1[4];                            // lane's 4 elems of h1[t]
  float hv1 = 0.f, hv2 = 0.f;              // own outputs (tid<HJ)
  int jg = b*HJ + tid;
  float blR=0,blZ=0,blN=0, biR=0,biZ=0,biN=0, bhR=0,bhZ=0,bhN=0;
  if (tid < HJ){
    blR = bhh_low [jg]; blZ = bhh_low [H+jg]; blN = bhh_low [2*H+jg];
    biR = bih_high[jg]; biZ = bih_high[H+jg]; biN = bih_high[2*H+jg];
    bhR = bhh_high[jg]; bhZ = bhh_high[H+jg]; bhN = bhh_high[2*H+jg];
  }

  for (int t = 0; t < T_STEPS; ++t){
    const int slot = (t & 1) * H;
    const unsigned tag = (unsigned)(t + 1);

    // ---- phase A finalize: h1[t] (gA valid from previous bottom / init)
    if (tid < HJ){
      const float* gx = Gx + t*G3;
      float giR = gA[tid]        + gx[jg];
      float giZ = gA[HJ+tid]     + gx[H+jg];
      float giN = gA[2*HJ+tid]   + gx[2*H+jg];
      float ghR = gA[ROWS+tid]      + blR;
      float ghZ = gA[ROWS+HJ+tid]   + blZ;
      float ghN = gA[ROWS+2*HJ+tid] + blN;
      float r = sigm(giR + ghR), z = sigm(giZ + ghZ);
      float n = tanhf(giN + r * ghN);
      hv1 = (1.f - z) * n + z * hv1;
      ast(h1s + slot + jg, packtv(tag, hv1));
      h1out[t*H + jg] = hv1;
    }
    // independent work in the shadow of h1 propagation:
    dot_one(w_m3, az, gB + ROWS, wv, lane);        // gh_B = Whh_high . h2[t-1]
    poll4(h1s + slot, lane, tag, nh1);             // gather h1[t]
    dot_one(w_m2, nh1, gB, wv, lane);              // gi_B = Wih_high . h1[t]
    __syncthreads();

    // ---- phase B finalize: h2[t]
    if (tid < HJ){
      float giR = gB[tid]        + biR;
      float giZ = gB[HJ+tid]     + biZ;
      float giN = gB[2*HJ+tid]   + biN;
      float ghR = gB[ROWS+tid]      + bhR;
      float ghZ = gB[ROWS+HJ+tid]   + bhZ;
      float ghN = gB[ROWS+2*HJ+tid] + bhN;
      float r = sigm(giR + ghR), z = sigm(giZ + ghZ);
      float n = tanhf(giN + r * ghN);
      hv2 = (1.f - z) * n + z * hv2;
      ast(h2s + slot + jg, packtv(tag, hv2));
    }
    if (t == T_STEPS - 1) break;
    // next step's phase-A dots, hiding h2 propagation:
    dot_one(w_m1, nh1, gA + ROWS, wv, lane);       // gh_A' = Whh_low . h1[t]
    poll4(h2s + slot, lane, tag, az);              // az = h2[t]
    dot_one(w_m0, az, gA, wv, lane);               // gi_A' = Wl2 . h2[t]
    __syncthreads();
  }
}

// ---------------------------------------------------------------- post
__global__ __launch_bounds__(G3) void post_kernel(
    const float* __restrict__ h1out,
    const float* __restrict__ W2v, const float* __restrict__ b2v,
    const float* __restrict__ W2m, const float* __restrict__ b2m,
    float* __restrict__ out)
{
  const int t = blockIdx.x, r = threadIdx.x;
  __shared__ float fs[H];
  if (r < H) fs[r] = eluf(h1out[t*H + r]);
  __syncthreads();
  const float* w = W2v + r * VF;
  float acc = b2v[r];
  #pragma unroll 8
  for (int c = 0; c < VF; ++c) acc += w[c] * fs[c];
  out[t*VIN + r] = sigm(acc);
  if (r < MIN_){
    const float* wm = W2m + r * VF;
    float am = b2m[r];
    #pragma unroll 8
    for (int c = 0; c < VF; ++c) am += wm[c] * fs[VF + c];
    out[T_STEPS*VIN + t*MIN_ + r] = tanhf(am);
  }
}

extern "C" void kernel_launch(void* const* d_in, const int* in_sizes, int n_in,
                              void* d_out, int out_size, void* d_ws, size_t ws_size,
                              hipStream_t stream)
{
  const float* v0       = (const float*)d_in[0];
  const float* m0       = (const float*)d_in[1];
  const float* W1v      = (const float*)d_in[2];
  const float* b1v      = (const float*)d_in[3];
  const float* W1m      = (const float*)d_in[4];
  const float* b1m      = (const float*)d_in[5];
  const float* Wih_low  = (const float*)d_in[6];
  const float* Whh_low  = (const float*)d_in[7];
  const float* bih_low  = (const float*)d_in[8];
  const float* bhh_low  = (const float*)d_in[9];
  const float* Wih_high = (const float*)d_in[10];
  const float* Whh_high = (const float*)d_in[11];
  const float* bih_high = (const float*)d_in[12];
  const float* bhh_high = (const float*)d_in[13];
  const float* W2v      = (const float*)d_in[14];
  const float* b2v      = (const float*)d_in[15];
  const float* W2m      = (const float*)d_in[16];
  const float* b2m      = (const float*)d_in[17];
  float* out = (float*)d_out;

  // ws layout
  char* ws = (char*)d_ws;
  u64*   h1s   = (u64*)(ws + 0);                 // 2*256*8 = 4096 B
  u64*   h2s   = (u64*)(ws + 4096);              // 4096 B
  float* h1out = (float*)(ws + 8192);            // 50*256*4 = 51200 B
  float* Gx    = (float*)(ws + 8192 + 51200);    // 50*768*4 = 153600 B

  hipMemsetAsync(ws, 0, 8192, stream);           // zero tagged-h arrays (tag 0 = initial h=0)

  featgx_kernel<<<T_STEPS, G3, 0, stream>>>(v0, m0, W1v, b1v, W1m, b1m,
                                            Wih_low, bih_low, Gx);
  scan_kernel<<<NB, BT, 0, stream>>>(Wih_low, Whh_low, Wih_high, Whh_high,
                                     Gx, bhh_low, bih_high, bhh_high,
                                     h1s, h2s, h1out);
  post_kernel<<<T_STEPS, G3, 0, stream>>>(h1out, W2v, b2v, W2m, b2m, out);
}

// Round 3
// 530.113 us; speedup vs baseline: 1.1995x; 1.0635x over previous
//
#include <hip/hip_runtime.h>
#include <hip/hip_fp16.h>

// Stacked GRU (T=50, B=1, H=256) on MI355X — round 3.
// Single fused kernel, 132 blocks x 256 threads:
//   blocks [0,32): persistent scan, H partitioned 8/block, weights f16 in LDS.
//   blocks [32,82): featgx for one t (writes tagged Gx).
//   blocks [82,132): post for one t (polls tagged h1 row, writes output).
// Cross-block exchange: 64-bit {tag,f32} relaxed agent-scope atomics, with
// per-consumer private copies (fan-out stores) and wave0-only polling.

#define T_STEPS 50
#define VIN 768
#define VF 128
#define MIN_ 2
#define H 256
#define G3 768

#define NB 32
#define BT 256
#define HJ 8
#define ROWS 24
#define WSLICE (4*ROWS*256)
#define BAIL 4000000

typedef unsigned long long u64;

__device__ __forceinline__ float sigm(float x){ return 1.0f/(1.0f+expf(-x)); }
__device__ __forceinline__ float eluf(float x){ return x > 0.0f ? x : expm1f(x); }

__device__ __forceinline__ u64 ald(const u64* p){
  return __hip_atomic_load(const_cast<u64*>(p), __ATOMIC_RELAXED, __HIP_MEMORY_SCOPE_AGENT);
}
__device__ __forceinline__ void ast(u64* p, u64 v){
  __hip_atomic_store(p, v, __ATOMIC_RELAXED, __HIP_MEMORY_SCOPE_AGENT);
}
__device__ __forceinline__ u64 packtv(unsigned tag, float v){
  union{ float f; unsigned u; } c; c.f = v;
  return ((u64)tag << 32) | (u64)c.u;
}
__device__ __forceinline__ float unpackv(u64 x){
  union{ unsigned u; float f; } c; c.u = (unsigned)x; return c.f;
}

// wave0: poll 4 tagged elems/lane from own private copy, deposit f32 into LDS
__device__ __forceinline__ void poll_to_lds(const u64* base, int lane, unsigned tag, float* h){
  u64 x0,x1,x2,x3; bool o0=false,o1=false,o2=false,o3=false;
  int guard = 0;
  while (true){
    if(!o0){ x0 = ald(base +       lane); if((unsigned)(x0>>32)==tag){ o0=true; h[      lane]=unpackv(x0);} }
    if(!o1){ x1 = ald(base +  64 + lane); if((unsigned)(x1>>32)==tag){ o1=true; h[ 64 + lane]=unpackv(x1);} }
    if(!o2){ x2 = ald(base + 128 + lane); if((unsigned)(x2>>32)==tag){ o2=true; h[128 + lane]=unpackv(x2);} }
    if(!o3){ x3 = ald(base + 192 + lane); if((unsigned)(x3>>32)==tag){ o3=true; h[192 + lane]=unpackv(x3);} }
    if (o0 & o1 & o2 & o3) break;
    if (++guard > BAIL) break;        // anti-wedge
    __builtin_amdgcn_s_sleep(1);
  }
}

// nrows row-dots of one 24x256 f16 matrix slice; lane's 4 swizzled cols are
// {lane, 64+lane, 128+lane, 192+lane}; lane0 writes out[lr].
__device__ __forceinline__ void dot_rows(const __half* wm, float a0, float a1, float a2, float a3,
                                         float* out, int base_lr, int nrows, int lane){
  #pragma unroll
  for (int rr = 0; rr < nrows; ++rr){
    const int lr = base_lr + rr;
    const __half2* w = reinterpret_cast<const __half2*>(wm + (lr << 8));
    float2 f0 = __half22float2(w[2*lane]);
    float2 f1 = __half22float2(w[2*lane+1]);
    float s = f0.x*a0 + f0.y*a1 + f1.x*a2 + f1.y*a3;
    #pragma unroll
    for (int off = 32; off; off >>= 1) s += __shfl_xor(s, off);
    if (lane == 0) out[lr] = s;
  }
}

__global__ __launch_bounds__(BT) void fused_kernel(
    const float* __restrict__ v0, const float* __restrict__ m0,
    const float* __restrict__ W1v, const float* __restrict__ b1v,
    const float* __restrict__ W1m, const float* __restrict__ b1m,
    const float* __restrict__ Wih_low, const float* __restrict__ Whh_low,
    const float* __restrict__ bih_low, const float* __restrict__ bhh_low,
    const float* __restrict__ Wih_high, const float* __restrict__ Whh_high,
    const float* __restrict__ bih_high, const float* __restrict__ bhh_high,
    const float* __restrict__ W2v, const float* __restrict__ b2v,
    const float* __restrict__ W2m, const float* __restrict__ b2m,
    float* __restrict__ out,
    u64* h1x, u64* h2x, u64* gxt, u64* h1ot)
{
  __shared__ __half w_lds[WSLICE];      // scan: 4 matrix slices, swizzled f16 (48 KB)
  __shared__ float h1n[H], h2n[H];      // scan: current h vectors
  __shared__ float gA[2*ROWS], gB[2*ROWS];
  __shared__ float hvs[HJ];
  __shared__ float xbuf[H];             // featgx: xs / post: fs

  const int bi  = blockIdx.x;
  const int tid = threadIdx.x;
  const int wv = tid >> 6, lane = tid & 63;

  if (bi < NB){
    // ================================================== scan role
    const int b = bi;
    for (int i = tid; i < WSLICE; i += BT){
      int c_sw = i & 255;
      int r2 = i >> 8;
      int lr = r2 % ROWS, m = r2 / ROWS;
      int c = (c_sw & 3)*64 + (c_sw >> 2);
      int g = lr / HJ, j = lr % HJ;
      int row = g*H + b*HJ + j;
      float v;
      if      (m == 0) v = Wih_low [row*(2*H) + H + c];
      else if (m == 1) v = Whh_low [row*H + c];
      else if (m == 2) v = Wih_high[row*H + c];
      else             v = Whh_high[row*H + c];
      w_lds[i] = __float2half(v);
    }
    if (tid < H){ h1n[tid] = 0.f; h2n[tid] = 0.f; }
    if (tid < 2*ROWS) gA[tid] = 0.f;
    __syncthreads();

    const __half* w_m0 = w_lds;               // Wih_low[:,256:512] (gi_A)
    const __half* w_m1 = w_lds + 1*ROWS*256;  // Whh_low   (gh_A)
    const __half* w_m2 = w_lds + 2*ROWS*256;  // Wih_high  (gi_B)
    const __half* w_m3 = w_lds + 3*ROWS*256;  // Whh_high  (gh_B)

    float hv1 = 0.f, hv2 = 0.f;
    float blR=0,blZ=0,blN=0, biR=0,biZ=0,biN=0, bhR=0,bhZ=0,bhN=0;
    float gxR=0, gxZ=0, gxN=0;
    const int jg = b*HJ + lane;               // valid for wv==0 && lane<HJ
    if (wv == 0 && lane < HJ){
      blR = bhh_low [jg]; blZ = bhh_low [H+jg]; blN = bhh_low [2*H+jg];
      biR = bih_high[jg]; biZ = bih_high[H+jg]; biN = bih_high[2*H+jg];
      bhR = bhh_high[jg]; bhZ = bhh_high[H+jg]; bhN = bhh_high[2*H+jg];
      // initial Gx[0] poll (featgx blocks run concurrently)
      const u64* g = gxt + jg;
      int guard = 0;
      while (true){
        u64 a0 = ald(g), a1 = ald(g + H), a2 = ald(g + 2*H);
        if (((unsigned)(a0>>32)==1u) & ((unsigned)(a1>>32)==1u) & ((unsigned)(a2>>32)==1u)){
          gxR = unpackv(a0); gxZ = unpackv(a1); gxN = unpackv(a2); break;
        }
        if (++guard > BAIL) break;
        __builtin_amdgcn_s_sleep(8);
      }
    }

    for (int t = 0; t < T_STEPS; ++t){
      const int par = t & 1;
      const unsigned tag = (unsigned)(t + 1);

      // ---- A finalize: h1[t]
      if (wv == 0 && lane < HJ){
        float giR = gA[lane]      + gxR, ghR = gA[ROWS+lane]      + blR;
        float giZ = gA[HJ+lane]   + gxZ, ghZ = gA[ROWS+HJ+lane]   + blZ;
        float giN = gA[2*HJ+lane] + gxN, ghN = gA[ROWS+2*HJ+lane] + blN;
        float r = sigm(giR + ghR), z = sigm(giZ + ghZ);
        float n = tanhf(giN + r * ghN);
        hv1 = (1.f - z) * n + z * hv1;
        hvs[lane] = hv1;
        ast(h1ot + (size_t)t*H + jg, packtv(1u, hv1));   // for post blocks
      }
      __syncthreads();                                   // sync1
      { int c = tid >> 3, j = tid & 7;                   // fan-out h1 to 32 copies
        ast(h1x + (((c<<1)+par)<<8) + (b<<3) + j, packtv(tag, hvs[j])); }
      if (wv == 0){
        poll_to_lds(h1x + (((b<<1)+par)<<8), lane, tag, h1n);
      } else {
        float a0=h2n[lane], a1=h2n[64+lane], a2=h2n[128+lane], a3=h2n[192+lane];
        dot_rows(w_m3, a0,a1,a2,a3, gB + ROWS, (wv-1)*8, 8, lane);   // gh_B
      }
      __syncthreads();                                   // sync2
      if (wv == 0){
        if (t + 1 < T_STEPS && lane < HJ){               // prefetch Gx[t+1]
          const u64* g = gxt + (size_t)(t+1)*G3 + jg;
          int guard = 0;
          while (true){
            u64 a0 = ald(g), a1 = ald(g + H), a2 = ald(g + 2*H);
            if (((unsigned)(a0>>32)==1u) & ((unsigned)(a1>>32)==1u) & ((unsigned)(a2>>32)==1u)){
              gxR = unpackv(a0); gxZ = unpackv(a1); gxN = unpackv(a2); break;
            }
            if (++guard > BAIL) break;
            __builtin_amdgcn_s_sleep(2);
          }
        }
      } else {
        float a0=h1n[lane], a1=h1n[64+lane], a2=h1n[128+lane], a3=h1n[192+lane];
        dot_rows(w_m2, a0,a1,a2,a3, gB, (wv-1)*8, 8, lane);          // gi_B
      }
      __syncthreads();                                   // sync3
      if (t == T_STEPS - 1) break;                       // h2[49] unused
      // ---- B finalize: h2[t]
      if (wv == 0 && lane < HJ){
        float giR = gB[lane]      + biR, ghR = gB[ROWS+lane]      + bhR;
        float giZ = gB[HJ+lane]   + biZ, ghZ = gB[ROWS+HJ+lane]   + bhZ;
        float giN = gB[2*HJ+lane] + biN, ghN = gB[ROWS+2*HJ+lane] + bhN;
        float r = sigm(giR + ghR), z = sigm(giZ + ghZ);
        float n = tanhf(giN + r * ghN);
        hv2 = (1.f - z) * n + z * hv2;
        hvs[lane] = hv2;
      }
      __syncthreads();                                   // sync4
      { int c = tid >> 3, j = tid & 7;                   // fan-out h2
        ast(h2x + (((c<<1)+par)<<8) + (b<<3) + j, packtv(tag, hvs[j])); }
      if (wv == 0){
        poll_to_lds(h2x + (((b<<1)+par)<<8), lane, tag, h2n);
      } else {
        float a0=h1n[lane], a1=h1n[64+lane], a2=h1n[128+lane], a3=h1n[192+lane];
        dot_rows(w_m1, a0,a1,a2,a3, gA + ROWS, (wv-1)*8, 8, lane);   // gh_A'
      }
      __syncthreads();                                   // sync5
      { float a0=h2n[lane], a1=h2n[64+lane], a2=h2n[128+lane], a3=h2n[192+lane];
        dot_rows(w_m0, a0,a1,a2,a3, gA, wv*6, 6, lane); }            // gi_A'
      __syncthreads();                                   // sync6
    }

  } else if (bi < NB + T_STEPS){
    // ================================================== featgx role
    const int t = bi - NB;
    { int j = tid >> 1, s = tid & 1;                     // 2 threads per v-output
      const float4* a4 = reinterpret_cast<const float4*>(v0 + (size_t)t*VIN) + s*96;
      const float4* w4 = reinterpret_cast<const float4*>(W1v + (size_t)j*VIN) + s*96;
      float p = 0.f;
      #pragma unroll 4
      for (int c = 0; c < 96; ++c){
        float4 a = a4[c], w = w4[c];
        p += a.x*w.x + a.y*w.y + a.z*w.z + a.w*w.w;
      }
      p += __shfl_xor(p, 1);
      if (s == 0) xbuf[j] = eluf(p + b1v[j]);
    }
    if (tid < VF){
      float am = b1m[tid] + W1m[tid*2]*m0[t*2] + W1m[tid*2+1]*m0[t*2+1];
      xbuf[VF + tid] = eluf(am);
    }
    __syncthreads();
    #pragma unroll
    for (int k = 0; k < 3; ++k){
      int r = k*256 + tid;
      const float4* w4 = reinterpret_cast<const float4*>(Wih_low + (size_t)r*(2*H));
      const float4* x4 = reinterpret_cast<const float4*>(xbuf);
      float acc = bih_low[r];
      #pragma unroll 8
      for (int c = 0; c < 64; ++c){
        float4 w = w4[c], x = x4[c];
        acc += w.x*x.x + w.y*x.y + w.z*x.z + w.w*x.w;
      }
      ast(gxt + (size_t)t*G3 + r, packtv(1u, acc));      // tagged publish
    }

  } else {
    // ================================================== post role
    const int t = bi - NB - T_STEPS;
    for (int i = 0; i < t; ++i) __builtin_amdgcn_s_sleep(32);   // ~0.85us * t backoff
    if (wv == 0){
      const u64* basep = h1ot + (size_t)t*H;
      u64 x0,x1,x2,x3; bool o0=false,o1=false,o2=false,o3=false;
      int guard = 0;
      while (true){
        if(!o0){ x0 = ald(basep +       lane); if((unsigned)(x0>>32)==1u){ o0=true; xbuf[      lane]=eluf(unpackv(x0)); } }
        if(!o1){ x1 = ald(basep +  64 + lane); if((unsigned)(x1>>32)==1u){ o1=true; xbuf[ 64 + lane]=eluf(unpackv(x1)); } }
        if(!o2){ x2 = ald(basep + 128 + lane); if((unsigned)(x2>>32)==1u){ o2=true; xbuf[128 + lane]=eluf(unpackv(x2)); } }
        if(!o3){ x3 = ald(basep + 192 + lane); if((unsigned)(x3>>32)==1u){ o3=true; xbuf[192 + lane]=eluf(unpackv(x3)); } }
        if (o0 & o1 & o2 & o3) break;
        if (++guard > BAIL) break;
        __builtin_amdgcn_s_sleep(16);
      }
    }
    __syncthreads();
    #pragma unroll
    for (int k = 0; k < 3; ++k){
      int r = k*256 + tid;
      const float4* w4 = reinterpret_cast<const float4*>(W2v + (size_t)r*VF);
      const float4* f4 = reinterpret_cast<const float4*>(xbuf);
      float acc = b2v[r];
      #pragma unroll 8
      for (int c = 0; c < 32; ++c){
        float4 w = w4[c], x = f4[c];
        acc += w.x*x.x + w.y*x.y + w.z*x.z + w.w*x.w;
      }
      out[(size_t)t*VIN + r] = sigm(acc);
    }
    if (tid < MIN_){
      const float* wm = W2m + tid*VF;
      float am = b2m[tid];
      #pragma unroll 8
      for (int c = 0; c < VF; ++c) am += wm[c] * xbuf[VF + c];
      out[(size_t)T_STEPS*VIN + t*MIN_ + tid] = tanhf(am);
    }
  }
}

extern "C" void kernel_launch(void* const* d_in, const int* in_sizes, int n_in,
                              void* d_out, int out_size, void* d_ws, size_t ws_size,
                              hipStream_t stream)
{
  const float* v0       = (const float*)d_in[0];
  const float* m0       = (const float*)d_in[1];
  const float* W1v      = (const float*)d_in[2];
  const float* b1v      = (const float*)d_in[3];
  const float* W1m      = (const float*)d_in[4];
  const float* b1m      = (const float*)d_in[5];
  const float* Wih_low  = (const float*)d_in[6];
  const float* Whh_low  = (const float*)d_in[7];
  const float* bih_low  = (const float*)d_in[8];
  const float* bhh_low  = (const float*)d_in[9];
  const float* Wih_high = (const float*)d_in[10];
  const float* Whh_high = (const float*)d_in[11];
  const float* bih_high = (const float*)d_in[12];
  const float* bhh_high = (const float*)d_in[13];
  const float* W2v      = (const float*)d_in[14];
  const float* b2v      = (const float*)d_in[15];
  const float* W2m      = (const float*)d_in[16];
  const float* b2m      = (const float*)d_in[17];
  float* out = (float*)d_out;

  // ws layout (8B-aligned). No memset needed: poison 0xAAAAAAAA != any tag (1..50).
  char* ws = (char*)d_ws;
  u64* h1x  = (u64*)(ws + 0);          // 32 copies x 2 par x 256 = 128 KB
  u64* h2x  = (u64*)(ws + 131072);     // 128 KB
  u64* gxt  = (u64*)(ws + 262144);     // 50*768*8 = 300 KB
  u64* h1ot = (u64*)(ws + 569344);     // 50*256*8 = 100 KB

  fused_kernel<<<NB + 2*T_STEPS, BT, 0, stream>>>(
      v0, m0, W1v, b1v, W1m, b1m,
      Wih_low, Whh_low, bih_low, bhh_low,
      Wih_high, Whh_high, bih_high, bhh_high,
      W2v, b2v, W2m, b2m, out,
      h1x, h2x, gxt, h1ot);
}

// Round 4
// 481.625 us; speedup vs baseline: 1.3203x; 1.1007x over previous
//
#include <hip/hip_runtime.h>
#include <hip/hip_fp16.h>

// Stacked GRU (T=50, B=1, H=256) on MI355X — round 4.
// Single fused kernel (132 blocks): 32 scan + 50 featgx + 50 post.
// Fix vs round 3: poll loops issue all tagged loads UNCONDITIONALLY each
// iteration (1 MALL round-trip/iter instead of 4 serialized ones), and
// producers fan out their h elements themselves right after finalize
// (no intervening __syncthreads). 4 syncs/step instead of 6.

#define T_STEPS 50
#define VIN 768
#define VF 128
#define MIN_ 2
#define H 256
#define G3 768

#define NB 32
#define BT 256
#define HJ 8
#define ROWS 24
#define WSLICE (4*ROWS*256)
#define BAIL 4000000

typedef unsigned long long u64;

__device__ __forceinline__ float sigm(float x){ return 1.0f/(1.0f+expf(-x)); }
__device__ __forceinline__ float eluf(float x){ return x > 0.0f ? x : expm1f(x); }

__device__ __forceinline__ u64 ald(const u64* p){
  return __hip_atomic_load(const_cast<u64*>(p), __ATOMIC_RELAXED, __HIP_MEMORY_SCOPE_AGENT);
}
__device__ __forceinline__ void ast(u64* p, u64 v){
  __hip_atomic_store(p, v, __ATOMIC_RELAXED, __HIP_MEMORY_SCOPE_AGENT);
}
__device__ __forceinline__ u64 packtv(unsigned tag, float v){
  union{ float f; unsigned u; } c; c.f = v;
  return ((u64)tag << 32) | (u64)c.u;
}
__device__ __forceinline__ float unpackv(u64 x){
  union{ unsigned u; float f; } c; c.u = (unsigned)x; return c.f;
}

// wave0 poll: 4 tagged elems/lane, grouped loads (1 round-trip per iter),
// per-lane divergent exit depositing into LDS.
__device__ __forceinline__ void poll_row_to_lds(const u64* base, int lane, unsigned tag, float* h){
  const u64* p = base + lane;
  int guard = 0;
  while (true){
    u64 x0 = ald(p), x1 = ald(p+64), x2 = ald(p+128), x3 = ald(p+192);
    bool ok = (((unsigned)(x0>>32))==tag) & (((unsigned)(x1>>32))==tag)
            & (((unsigned)(x2>>32))==tag) & (((unsigned)(x3>>32))==tag);
    if (ok | (++guard > BAIL)){
      h[      lane] = unpackv(x0);
      h[ 64 + lane] = unpackv(x1);
      h[128 + lane] = unpackv(x2);
      h[192 + lane] = unpackv(x3);
      break;
    }
  }
}

// nrows row-dots of one 24x256 f16 slice; lane's 4 swizzled cols are
// {lane, 64+lane, 128+lane, 192+lane}; lane0 writes out[lr].
__device__ __forceinline__ void dot_rows(const __half* wm, float a0, float a1, float a2, float a3,
                                         float* out, int base_lr, int nrows, int lane){
  #pragma unroll
  for (int rr = 0; rr < nrows; ++rr){
    const int lr = base_lr + rr;
    const __half2* w = reinterpret_cast<const __half2*>(wm + (lr << 8));
    float2 f0 = __half22float2(w[2*lane]);
    float2 f1 = __half22float2(w[2*lane+1]);
    float s = f0.x*a0 + f0.y*a1 + f1.x*a2 + f1.y*a3;
    #pragma unroll
    for (int off = 32; off; off >>= 1) s += __shfl_xor(s, off);
    if (lane == 0) out[lr] = s;
  }
}

__global__ __launch_bounds__(BT) void fused_kernel(
    const float* __restrict__ v0, const float* __restrict__ m0,
    const float* __restrict__ W1v, const float* __restrict__ b1v,
    const float* __restrict__ W1m, const float* __restrict__ b1m,
    const float* __restrict__ Wih_low, const float* __restrict__ Whh_low,
    const float* __restrict__ bih_low, const float* __restrict__ bhh_low,
    const float* __restrict__ Wih_high, const float* __restrict__ Whh_high,
    const float* __restrict__ bih_high, const float* __restrict__ bhh_high,
    const float* __restrict__ W2v, const float* __restrict__ b2v,
    const float* __restrict__ W2m, const float* __restrict__ b2m,
    float* __restrict__ out,
    u64* h1x, u64* h2x, u64* gxt, u64* h1ot)
{
  __shared__ __half w_lds[WSLICE];
  __shared__ float h1n[H], h2n[H];
  __shared__ float gA[2*ROWS], gB[2*ROWS];
  __shared__ float xbuf[H];

  const int bi  = blockIdx.x;
  const int tid = threadIdx.x;
  const int wv = tid >> 6, lane = tid & 63;

  if (bi < NB){
    // ================================================== scan role
    const int b = bi;
    for (int i = tid; i < WSLICE; i += BT){
      int c_sw = i & 255;
      int r2 = i >> 8;
      int lr = r2 % ROWS, m = r2 / ROWS;
      int c = (c_sw & 3)*64 + (c_sw >> 2);
      int g = lr / HJ, j = lr % HJ;
      int row = g*H + b*HJ + j;
      float v;
      if      (m == 0) v = Wih_low [row*(2*H) + H + c];
      else if (m == 1) v = Whh_low [row*H + c];
      else if (m == 2) v = Wih_high[row*H + c];
      else             v = Whh_high[row*H + c];
      w_lds[i] = __float2half(v);
    }
    if (tid < H) h2n[tid] = 0.f;
    if (tid < 2*ROWS) gA[tid] = 0.f;
    __syncthreads();

    const __half* w_m0 = w_lds;               // Wih_low[:,256:512] (gi_A)
    const __half* w_m1 = w_lds + 1*ROWS*256;  // Whh_low   (gh_A)
    const __half* w_m2 = w_lds + 2*ROWS*256;  // Wih_high  (gi_B)
    const __half* w_m3 = w_lds + 3*ROWS*256;  // Whh_high  (gh_B)

    float hv1 = 0.f, hv2 = 0.f;
    float blR=0,blZ=0,blN=0, biR=0,biZ=0,biN=0, bhR=0,bhZ=0,bhN=0;
    float gxR=0, gxZ=0, gxN=0;
    const int jg = b*HJ + lane;               // valid for wv==0 && lane<HJ
    if (wv == 0 && lane < HJ){
      blR = bhh_low [jg]; blZ = bhh_low [H+jg]; blN = bhh_low [2*H+jg];
      biR = bih_high[jg]; biZ = bih_high[H+jg]; biN = bih_high[2*H+jg];
      bhR = bhh_high[jg]; bhZ = bhh_high[H+jg]; bhN = bhh_high[2*H+jg];
      const u64* g = gxt + jg;                // initial Gx[0] poll
      int guard = 0;
      while (true){
        u64 a0 = ald(g), a1 = ald(g + H), a2 = ald(g + 2*H);
        bool ok = (((unsigned)(a0>>32))==1u) & (((unsigned)(a1>>32))==1u) & (((unsigned)(a2>>32))==1u);
        if (ok | (++guard > BAIL)){ gxR=unpackv(a0); gxZ=unpackv(a1); gxN=unpackv(a2); break; }
        __builtin_amdgcn_s_sleep(4);
      }
    }

    for (int t = 0; t < T_STEPS; ++t){
      const int par = t & 1;
      const unsigned tag = (unsigned)(t + 1);

      // ---- segment 1: A finalize + fanout (wave0) | gh_B dot (waves 1-3)
      if (wv == 0){
        if (lane < HJ){
          float giR = gA[lane]      + gxR, ghR = gA[ROWS+lane]      + blR;
          float giZ = gA[HJ+lane]   + gxZ, ghZ = gA[ROWS+HJ+lane]   + blZ;
          float giN = gA[2*HJ+lane] + gxN, ghN = gA[ROWS+2*HJ+lane] + blN;
          float r = sigm(giR + ghR), z = sigm(giZ + ghZ);
          float n = tanhf(giN + r * ghN);
          hv1 = (1.f - z) * n + z * hv1;
          ast(h1ot + (size_t)t*H + jg, packtv(1u, hv1));
          u64 pk = packtv(tag, hv1);
          u64* dst = h1x + (par<<8) + (b<<3) + lane;
          #pragma unroll
          for (int c = 0; c < NB; ++c) ast(dst + (c<<9), pk);
        }
      } else {
        float a0=h2n[lane], a1=h2n[64+lane], a2=h2n[128+lane], a3=h2n[192+lane];
        dot_rows(w_m3, a0,a1,a2,a3, gB + ROWS, (wv-1)*8, 8, lane);   // gh_B
      }
      if (t == T_STEPS - 1) break;
      if (wv == 0) poll_row_to_lds(h1x + (par<<8) + ((b&~0)<<0)*0 + ((b<<9)), lane, tag, h1n);
      __syncthreads();                                   // sync1: h1n + gh_B ready

      // ---- segment 2: gi_B (waves 1-3) | Gx[t+1] prefetch (wave0)
      if (wv == 0){
        if (lane < HJ){
          const u64* g = gxt + (size_t)(t+1)*G3 + jg;
          int guard = 0;
          while (true){
            u64 a0 = ald(g), a1 = ald(g + H), a2 = ald(g + 2*H);
            bool ok = (((unsigned)(a0>>32))==1u) & (((unsigned)(a1>>32))==1u) & (((unsigned)(a2>>32))==1u);
            if (ok | (++guard > BAIL)){ gxR=unpackv(a0); gxZ=unpackv(a1); gxN=unpackv(a2); break; }
            __builtin_amdgcn_s_sleep(2);
          }
        }
      } else {
        float a0=h1n[lane], a1=h1n[64+lane], a2=h1n[128+lane], a3=h1n[192+lane];
        dot_rows(w_m2, a0,a1,a2,a3, gB, (wv-1)*8, 8, lane);          // gi_B
      }
      __syncthreads();                                   // sync2: gB complete

      // ---- segment 3: B finalize + fanout (wave0) | gh_A' (waves 1-3)
      if (wv == 0){
        if (lane < HJ){
          float giR = gB[lane]      + biR, ghR = gB[ROWS+lane]      + bhR;
          float giZ = gB[HJ+lane]   + biZ, ghZ = gB[ROWS+HJ+lane]   + bhZ;
          float giN = gB[2*HJ+lane] + biN, ghN = gB[ROWS+2*HJ+lane] + bhN;
          float r = sigm(giR + ghR), z = sigm(giZ + ghZ);
          float n = tanhf(giN + r * ghN);
          hv2 = (1.f - z) * n + z * hv2;
          u64 pk = packtv(tag, hv2);
          u64* dst = h2x + (par<<8) + (b<<3) + lane;
          #pragma unroll
          for (int c = 0; c < NB; ++c) ast(dst + (c<<9), pk);
        }
      } else {
        float a0=h1n[lane], a1=h1n[64+lane], a2=h1n[128+lane], a3=h1n[192+lane];
        dot_rows(w_m1, a0,a1,a2,a3, gA + ROWS, (wv-1)*8, 8, lane);   // gh_A'
      }
      if (wv == 0) poll_row_to_lds(h2x + (par<<8) + (b<<9), lane, tag, h2n);
      __syncthreads();                                   // sync3: h2n + gh_A' ready

      // ---- segment 4: gi_A' (all 4 waves, 6 rows each)
      { float a0=h2n[lane], a1=h2n[64+lane], a2=h2n[128+lane], a3=h2n[192+lane];
        dot_rows(w_m0, a0,a1,a2,a3, gA, wv*6, 6, lane); }            // gi_A'
      __syncthreads();                                   // sync4
    }

  } else if (bi < NB + T_STEPS){
    // ================================================== featgx role
    const int t = bi - NB;
    { int j = tid >> 1, s = tid & 1;
      const float4* a4 = reinterpret_cast<const float4*>(v0 + (size_t)t*VIN) + s*96;
      const float4* w4 = reinterpret_cast<const float4*>(W1v + (size_t)j*VIN) + s*96;
      float p = 0.f;
      #pragma unroll 4
      for (int c = 0; c < 96; ++c){
        float4 a = a4[c], w = w4[c];
        p += a.x*w.x + a.y*w.y + a.z*w.z + a.w*w.w;
      }
      p += __shfl_xor(p, 1);
      if (s == 0) xbuf[j] = eluf(p + b1v[j]);
    }
    if (tid < VF){
      float am = b1m[tid] + W1m[tid*2]*m0[t*2] + W1m[tid*2+1]*m0[t*2+1];
      xbuf[VF + tid] = eluf(am);
    }
    __syncthreads();
    #pragma unroll
    for (int k = 0; k < 3; ++k){
      int r = k*256 + tid;
      const float4* w4 = reinterpret_cast<const float4*>(Wih_low + (size_t)r*(2*H));
      const float4* x4 = reinterpret_cast<const float4*>(xbuf);
      float acc = bih_low[r];
      #pragma unroll 8
      for (int c = 0; c < 64; ++c){
        float4 w = w4[c], x = x4[c];
        acc += w.x*x.x + w.y*x.y + w.z*x.z + w.w*x.w;
      }
      ast(gxt + (size_t)t*G3 + r, packtv(1u, acc));
    }

  } else {
    // ================================================== post role
    const int t = bi - NB - T_STEPS;
    for (int i = 0; i < t; ++i) __builtin_amdgcn_s_sleep(32);   // staggered start
    if (wv == 0){
      const u64* p = h1ot + (size_t)t*H + lane;
      int guard = 0;
      while (true){
        u64 x0 = ald(p), x1 = ald(p+64), x2 = ald(p+128), x3 = ald(p+192);
        bool ok = (((unsigned)(x0>>32))==1u) & (((unsigned)(x1>>32))==1u)
                & (((unsigned)(x2>>32))==1u) & (((unsigned)(x3>>32))==1u);
        if (ok | (++guard > BAIL)){
          xbuf[      lane] = eluf(unpackv(x0));
          xbuf[ 64 + lane] = eluf(unpackv(x1));
          xbuf[128 + lane] = eluf(unpackv(x2));
          xbuf[192 + lane] = eluf(unpackv(x3));
          break;
        }
        __builtin_amdgcn_s_sleep(8);
      }
    }
    __syncthreads();
    #pragma unroll
    for (int k = 0; k < 3; ++k){
      int r = k*256 + tid;
      const float4* w4 = reinterpret_cast<const float4*>(W2v + (size_t)r*VF);
      const float4* f4 = reinterpret_cast<const float4*>(xbuf);
      float acc = b2v[r];
      #pragma unroll 8
      for (int c = 0; c < 32; ++c){
        float4 w = w4[c], x = f4[c];
        acc += w.x*x.x + w.y*x.y + w.z*x.z + w.w*x.w;
      }
      out[(size_t)t*VIN + r] = sigm(acc);
    }
    if (tid < MIN_){
      const float* wm = W2m + tid*VF;
      float am = b2m[tid];
      #pragma unroll 8
      for (int c = 0; c < VF; ++c) am += wm[c] * xbuf[VF + c];
      out[(size_t)T_STEPS*VIN + t*MIN_ + tid] = tanhf(am);
    }
  }
}

extern "C" void kernel_launch(void* const* d_in, const int* in_sizes, int n_in,
                              void* d_out, int out_size, void* d_ws, size_t ws_size,
                              hipStream_t stream)
{
  const float* v0       = (const float*)d_in[0];
  const float* m0       = (const float*)d_in[1];
  const float* W1v      = (const float*)d_in[2];
  const float* b1v      = (const float*)d_in[3];
  const float* W1m      = (const float*)d_in[4];
  const float* b1m      = (const float*)d_in[5];
  const float* Wih_low  = (const float*)d_in[6];
  const float* Whh_low  = (const float*)d_in[7];
  const float* bih_low  = (const float*)d_in[8];
  const float* bhh_low  = (const float*)d_in[9];
  const float* Wih_high = (const float*)d_in[10];
  const float* Whh_high = (const float*)d_in[11];
  const float* bih_high = (const float*)d_in[12];
  const float* bhh_high = (const float*)d_in[13];
  const float* W2v      = (const float*)d_in[14];
  const float* b2v      = (const float*)d_in[15];
  const float* W2m      = (const float*)d_in[16];
  const float* b2m      = (const float*)d_in[17];
  float* out = (float*)d_out;

  // ws layout (8B-aligned). No memset needed: 0xAA...AA tag != any tag used.
  // h1x/h2x: [copy c][par][256] u64 -> region for consumer b at (b<<9)+(par<<8).
  char* ws = (char*)d_ws;
  u64* h1x  = (u64*)(ws + 0);          // 32*2*256*8 = 128 KB
  u64* h2x  = (u64*)(ws + 131072);     // 128 KB
  u64* gxt  = (u64*)(ws + 262144);     // 50*768*8 = 300 KB
  u64* h1ot = (u64*)(ws + 569344);     // 50*256*8 = 100 KB

  fused_kernel<<<NB + 2*T_STEPS, BT, 0, stream>>>(
      v0, m0, W1v, b1v, W1m, b1m,
      Wih_low, Whh_low, bih_low, bhh_low,
      Wih_high, Whh_high, bih_high, bhh_high,
      W2v, b2v, W2m, b2m, out,
      h1x, h2x, gxt, h1ot);
}